// Round 8
// baseline (1524.827 us; speedup 1.0000x reference)
//
#include <hip/hip_runtime.h>

#define BLK 256

typedef __bf16 bf16;
typedef __bf16 bf16x8 __attribute__((ext_vector_type(8)));
typedef float f32x4 __attribute__((ext_vector_type(4)));

__device__ __forceinline__ float sigm(float x) { return 1.f / (1.f + __expf(-x)); }
__device__ __forceinline__ float tanh_(float x) {
    x = fminf(fmaxf(x, -15.f), 15.f);
    float e = __expf(2.f * x);
    return (e - 1.f) / (e + 1.f);
}

// async 16B global->LDS; lds dest is wave-uniform base (+ lane*16 implicit)
__device__ __forceinline__ void gl2lds(const bf16* g, bf16* l) {
    __builtin_amdgcn_global_load_lds((const __attribute__((address_space(1))) void*)g,
                                     (__attribute__((address_space(3))) void*)l, 16, 0, 0);
}

// ---------------- fused prep: tiled transposes + casts + bz ----------------
__global__ __launch_bounds__(256) void k_prep(
    const float* __restrict__ src, const float* __restrict__ tgt,
    const float* __restrict__ WH, const float* __restrict__ bH,
    const float* __restrict__ Wk, const float* __restrict__ Wr,
    const float* __restrict__ bl,
    bf16* __restrict__ srcb, bf16* __restrict__ tgtb,
    bf16* __restrict__ WHhi, bf16* __restrict__ WHlo,
    bf16* __restrict__ Wrhi, bf16* __restrict__ Wrlo,
    bf16* __restrict__ P2, float* __restrict__ bz) {
    __shared__ float tile[64][65];
    const int bid = blockIdx.x, t = threadIdx.x;
    if (bid < 512) {
        const float* in = (bid < 256) ? Wr : Wk;
        bf16* ohi = (bid < 256) ? Wrhi : P2;
        bf16* olo = (bid < 256) ? Wrlo : nullptr;
        const int b = bid & 255;
        const int tr = b >> 5, tc = b & 31;  // 8 k-blocks x 32 c-blocks of 64x64
#pragma unroll
        for (int q = 0; q < 16; q++) {
            int idx = q * 256 + t, lr = idx >> 6, lc = idx & 63;
            tile[lr][lc] = in[(size_t)(tr * 64 + lr) * 2048 + tc * 64 + lc];
        }
        __syncthreads();
#pragma unroll
        for (int q = 0; q < 16; q++) {
            int idx = q * 256 + t, lr = idx >> 6, lc = idx & 63;
            float v = tile[lc][lr];
            size_t o = (size_t)(tc * 64 + lr) * 512 + tr * 64 + lc;
            bf16 h = (bf16)v;
            ohi[o] = h;
            if (olo) olo[o] = (bf16)(v - (float)h);
        }
    } else if (bid < 520) {
        int c = (bid - 512) * 256 + t;
        float s = bl[c];
        for (int k = 0; k < 512; k++) s += bH[k] * Wr[(size_t)k * 2048 + c];
        bz[c] = s;
    } else {
        const int gt = (bid - 520) * 256 + t, NT = 504 * 256;
        for (int id = gt; id < 1048576; id += NT) srcb[id] = (bf16)src[id];
        for (int id = gt; id < 1048576; id += NT) tgtb[id] = (bf16)tgt[id];
        for (int id = gt; id < 524288; id += NT) {
            float v = WH[id];
            bf16 h = (bf16)v;
            WHhi[id] = h;
            WHlo[id] = (bf16)(v - (float)h);
        }
    }
}

// ---------------- P-matrix builder GEMM (proven, grid 256) ----------------
__global__ __launch_bounds__(256, 4) void k_gemmP(
    const bf16* __restrict__ Wrhi, const bf16* __restrict__ Wrlo,
    const bf16* __restrict__ WHhi, const bf16* __restrict__ WHlo,
    const float* __restrict__ Wk,
    bf16* __restrict__ P1, bf16* __restrict__ P3,
    bf16* __restrict__ P4, bf16* __restrict__ P5) {
    __shared__ __align__(16) bf16 At[64 * 64];
    __shared__ __align__(16) bf16 Bt[128 * 64];
    const int t = threadIdx.x, w = t >> 6, l = t & 63;
    const int m0 = (blockIdx.x >> 3) * 64, n0 = (blockIdx.x & 7) * 128;
    f32x4 acc[2][4] = {};
    const bf16* Aps[3] = {Wrhi, Wrlo, Wrhi};
    const bf16* Bps[3] = {WHhi, WHhi, WHlo};
    for (int ph = 0; ph < 3; ph++) {
        const bf16* Ap = Aps[ph] + (size_t)m0 * 512;
        const bf16* Bp = Bps[ph] + (size_t)n0 * 512;
        for (int kt = 0; kt < 8; kt++) {
            int k0 = kt * 64;
            __syncthreads();
#pragma unroll
            for (int q = 0; q < 2; q++) {
                int pp = q * 256 + t;
                int r = pp >> 3, c = (pp & 7) ^ (r & 7);
                gl2lds(Ap + (size_t)r * 512 + k0 + c * 8, &At[(q * 256 + w * 64) * 8]);
            }
#pragma unroll
            for (int q = 0; q < 4; q++) {
                int pp = q * 256 + t;
                int r = pp >> 3, c = (pp & 7) ^ (r & 7);
                gl2lds(Bp + (size_t)r * 512 + k0 + c * 8, &Bt[(q * 256 + w * 64) * 8]);
            }
            __syncthreads();
#pragma unroll
            for (int ks = 0; ks < 2; ks++) {
                int c = ks * 4 + (l >> 4);
                bf16x8 af[2], bb[4];
#pragma unroll
                for (int mt = 0; mt < 2; mt++) {
                    int r = (w >> 1) * 32 + mt * 16 + (l & 15);
                    af[mt] = *(const bf16x8*)&At[(r * 8 + (c ^ (r & 7))) * 8];
                }
#pragma unroll
                for (int g = 0; g < 4; g++) {
                    int r = g * 32 + (w & 1) * 16 + (l & 15);
                    bb[g] = *(const bf16x8*)&Bt[(r * 8 + (c ^ (r & 7))) * 8];
                }
#pragma unroll
                for (int mt = 0; mt < 2; mt++)
#pragma unroll
                    for (int g = 0; g < 4; g++)
                        acc[mt][g] = __builtin_amdgcn_mfma_f32_16x16x32_bf16(
                            af[mt], bb[g], acc[mt][g], 0, 0, 0);
            }
        }
    }
    const bool hihalf = (n0 >= 512);
#pragma unroll
    for (int mt = 0; mt < 2; mt++) {
#pragma unroll
        for (int g = 0; g < 4; g++) {
            int np = n0 + g * 32 + (w & 1) * 16 + (l & 15);
#pragma unroll
            for (int r = 0; r < 4; r++) {
                int c = m0 + (w >> 1) * 32 + mt * 16 + ((l >> 4) << 2) + r;
                float v = acc[mt][g][r];
                if (!hihalf) {
                    P4[(size_t)c * 512 + np] = (bf16)v;
                    P1[(size_t)c * 512 + np] = (bf16)(v + Wk[(size_t)np * 2048 + c]);
                } else {
                    int kk = np - 512;
                    P3[(size_t)c * 512 + kk] = (bf16)v;
                    P5[(size_t)c * 512 + kk] = (bf16)(v + Wk[(size_t)kk * 2048 + c]);
                }
            }
        }
    }
}

// ---------------- shared helpers for diag kernels ----------------
__device__ __forceinline__ int build_panels(int i, int d, int side,
                                            const bf16* srcb, const bf16* tgtb,
                                            const bf16* shR, const bf16* thR,
                                            const bf16* P1, const bf16* P2,
                                            const bf16* P3, const bf16* P4,
                                            const bf16* P5, const bf16** A,
                                            const bf16** W) {
    const int j = d - i;
    const size_t stI = (size_t)i * 32768, stJ = (size_t)j * 32768;
    int nh = 0;
    if (side == 0) {  // z_s
        A[nh] = (j == 0 ? srcb : shR) + stI;
        W[nh] = (j == 0 ? P2 : P1);
        nh++;
        if (i > 0) { A[nh] = thR + stJ; W[nh] = P3; nh++; }
    } else {  // z_t
        if (j > 0) { A[nh] = shR + stI; W[nh] = P4; nh++; }
        A[nh] = (i == 0 ? tgtb : thR) + stJ;
        W[nh] = (i == 0 ? P2 : P5);
        nh++;
    }
    return nh;
}

// ---------------- small-diag kernel: single cell, K-tile=128 (R7-proven) -------
__global__ __launch_bounds__(256, 3) void k_diag3(
    int d, int i_lo,
    const bf16* __restrict__ srcb, const bf16* __restrict__ tgtb,
    const bf16* __restrict__ P1, const bf16* __restrict__ P2,
    const bf16* __restrict__ P3, const bf16* __restrict__ P4,
    const bf16* __restrict__ P5,
    const float* __restrict__ bz,
    const bf16* __restrict__ shR, bf16* __restrict__ shW,
    const bf16* __restrict__ thR, bf16* __restrict__ thW,
    float* __restrict__ sc, float* __restrict__ tc,
    float* __restrict__ out) {
    __shared__ __align__(16) bf16 At[64 * 128];   // 16 KB
    __shared__ __align__(16) bf16 Bt[128 * 128];  // 32 KB
    const int t = threadIdx.x, w = t >> 6, l = t & 63;
    const int cell = blockIdx.x >> 5, sub = blockIdx.x & 31;
    const int side = sub >> 4, ch0 = (sub & 15) << 5;
    const int i = i_lo + cell, j = d - i;
    const size_t stI = (size_t)i * 32768, stJ = (size_t)j * 32768;

    const bf16 *Ah[2], *Wh[2];
    const int nh = build_panels(i, d, side, srcb, tgtb, shR, thR, P1, P2, P3, P4, P5, Ah, Wh);

    f32x4 acc[2][4] = {};
    for (int hh = 0; hh < nh; hh++) {
        const bf16* Ap = Ah[hh];
        const bf16* Wp = Wh[hh];
#pragma unroll 1
        for (int kt = 0; kt < 4; kt++) {
            int k0 = kt * 128;
            __syncthreads();
#pragma unroll
            for (int q = 0; q < 4; q++) {
                int pp = q * 256 + t;
                int r = pp >> 4, c = (pp & 15) ^ (r & 15);
                gl2lds(Ap + (size_t)r * 512 + k0 + c * 8, &At[(q * 256 + w * 64) * 8]);
            }
#pragma unroll
            for (int q = 0; q < 8; q++) {
                int pp = q * 256 + t;
                int r = pp >> 4, c = (pp & 15) ^ (r & 15);
                int g = r >> 5;
                gl2lds(Wp + (size_t)(g * 512 + ch0 + (r & 31)) * 512 + k0 + c * 8,
                       &Bt[(q * 256 + w * 64) * 8]);
            }
            __syncthreads();
#pragma unroll
            for (int ks = 0; ks < 4; ks++) {
                int cq = ks * 4 + (l >> 4);
                bf16x8 af[2], bb[4];
#pragma unroll
                for (int mt = 0; mt < 2; mt++) {
                    int r = (w >> 1) * 32 + mt * 16 + (l & 15);
                    af[mt] = *(const bf16x8*)&At[(r * 16 + (cq ^ (r & 15))) * 8];
                }
#pragma unroll
                for (int g = 0; g < 4; g++) {
                    int r = g * 32 + (w & 1) * 16 + (l & 15);
                    bb[g] = *(const bf16x8*)&Bt[(r * 16 + (cq ^ (r & 15))) * 8];
                }
#pragma unroll
                for (int mt = 0; mt < 2; mt++)
#pragma unroll
                    for (int g = 0; g < 4; g++)
                        acc[mt][g] = __builtin_amdgcn_mfma_f32_16x16x32_bf16(
                            af[mt], bb[g], acc[mt][g], 0, 0, 0);
            }
        }
    }

    const int h = ch0 + (w & 1) * 16 + (l & 15);
    float bzv[4];
#pragma unroll
    for (int g = 0; g < 4; g++) bzv[g] = bz[g * 512 + h];
#pragma unroll
    for (int mt = 0; mt < 2; mt++) {
#pragma unroll
        for (int r = 0; r < 4; r++) {
            int b = (w >> 1) * 32 + mt * 16 + ((l >> 4) << 2) + r;
            float zi = acc[mt][0][r] + bzv[0];
            float zf = acc[mt][1][r] + bzv[1];
            float zg = acc[mt][2][r] + bzv[2];
            float zo = acc[mt][3][r] + bzv[3];
            if (side == 0) {
                size_t off = stI + (size_t)b * 512 + h;
                float cold = (j == 0) ? 0.f : sc[off];
                float c2 = sigm(zf) * cold + sigm(zi) * tanh_(zg);
                float h2 = sigm(zo) * tanh_(c2);
                sc[off] = c2;
                shW[off] = (bf16)h2;
                if (j == 31) out[off] = h2;  // source_out[i]
            } else {
                size_t off = stJ + (size_t)b * 512 + h;
                float cold = (i == 0) ? 0.f : tc[off];
                float c2 = sigm(zf) * cold + sigm(zi) * tanh_(zg);
                float h2 = sigm(zo) * tanh_(c2);
                tc[off] = c2;
                thW[off] = (bf16)h2;
                if (i == 31) out[1048576 + off] = h2;  // t_final[0][j]
            }
        }
    }
}

// ---------------- paired-cell diag kernel: shared B, async A, kt=64 ----------------
// Per round: stage B strip (shared by both cells) + both A tiles via
// global_load_lds; 32 MFMA/wave per round. LDS 32 KB -> >=3 blocks/CU.
__device__ __forceinline__ void phase4(const bf16* __restrict__ A0,
                                       const bf16* __restrict__ A1,
                                       const bf16* __restrict__ Wp, int ch0, int t,
                                       int w, int l, bf16* __restrict__ At0,
                                       bf16* __restrict__ At1, bf16* __restrict__ Bt,
                                       f32x4 (*acc0)[4], f32x4 (*acc1)[4]) {
#pragma unroll 1
    for (int kt = 0; kt < 8; kt++) {
        int k0 = kt * 64;
        __syncthreads();
#pragma unroll
        for (int q = 0; q < 4; q++) {
            int pp = q * 256 + t;
            int r = pp >> 3, c = (pp & 7) ^ (r & 7), g = r >> 5;
            gl2lds(Wp + (size_t)(g * 512 + ch0 + (r & 31)) * 512 + k0 + c * 8,
                   &Bt[(q * 256 + w * 64) * 8]);
        }
#pragma unroll
        for (int q = 0; q < 2; q++) {
            int pp = q * 256 + t;
            int r = pp >> 3, c = (pp & 7) ^ (r & 7);
            gl2lds(A0 + (size_t)r * 512 + k0 + c * 8, &At0[(q * 256 + w * 64) * 8]);
        }
        if (A1) {
#pragma unroll
            for (int q = 0; q < 2; q++) {
                int pp = q * 256 + t;
                int r = pp >> 3, c = (pp & 7) ^ (r & 7);
                gl2lds(A1 + (size_t)r * 512 + k0 + c * 8, &At1[(q * 256 + w * 64) * 8]);
            }
        }
        __syncthreads();
#pragma unroll
        for (int ks = 0; ks < 2; ks++) {
            int cq = ks * 4 + (l >> 4);
            bf16x8 af0[2], af1[2], bb[4];
#pragma unroll
            for (int mt = 0; mt < 2; mt++) {
                int r = (w >> 1) * 32 + mt * 16 + (l & 15);
                int o = (r * 8 + (cq ^ (r & 7))) * 8;
                af0[mt] = *(const bf16x8*)&At0[o];
                if (A1) af1[mt] = *(const bf16x8*)&At1[o];
            }
#pragma unroll
            for (int g = 0; g < 4; g++) {
                int r = g * 32 + (w & 1) * 16 + (l & 15);
                bb[g] = *(const bf16x8*)&Bt[(r * 8 + (cq ^ (r & 7))) * 8];
            }
#pragma unroll
            for (int mt = 0; mt < 2; mt++)
#pragma unroll
                for (int g = 0; g < 4; g++) {
                    acc0[mt][g] = __builtin_amdgcn_mfma_f32_16x16x32_bf16(
                        af0[mt], bb[g], acc0[mt][g], 0, 0, 0);
                    if (A1)
                        acc1[mt][g] = __builtin_amdgcn_mfma_f32_16x16x32_bf16(
                            af1[mt], bb[g], acc1[mt][g], 0, 0, 0);
                }
        }
    }
}

__global__ __launch_bounds__(256, 3) void k_diag4(
    int d, int i_lo, int i_hi,
    const bf16* __restrict__ srcb, const bf16* __restrict__ tgtb,
    const bf16* __restrict__ P1, const bf16* __restrict__ P2,
    const bf16* __restrict__ P3, const bf16* __restrict__ P4,
    const bf16* __restrict__ P5,
    const float* __restrict__ bz,
    const bf16* __restrict__ shR, bf16* __restrict__ shW,
    const bf16* __restrict__ thR, bf16* __restrict__ thW,
    float* __restrict__ sc, float* __restrict__ tc,
    float* __restrict__ out) {
    __shared__ __align__(16) bf16 At0[64 * 64];  // 8 KB
    __shared__ __align__(16) bf16 At1[64 * 64];  // 8 KB
    __shared__ __align__(16) bf16 Bt[128 * 64];  // 16 KB
    const int t = threadIdx.x, w = t >> 6, l = t & 63;
    const int pairI = blockIdx.x >> 5, sub = blockIdx.x & 31;
    const int side = sub >> 4, ch0 = (sub & 15) << 5;
    const int ia = i_lo + pairI * 2, ib = ia + 1;
    const bool v1 = (ib <= i_hi);

    const bf16 *A0[2], *W0[2], *A1[2], *W1[2];
    const int nh0 = build_panels(ia, d, side, srcb, tgtb, shR, thR, P1, P2, P3, P4, P5, A0, W0);
    int nh1 = 0;
    if (v1) nh1 = build_panels(ib, d, side, srcb, tgtb, shR, thR, P1, P2, P3, P4, P5, A1, W1);
    const bool share = v1 && (nh0 == nh1) && (W0[0] == W1[0]) && (nh0 < 2 || W0[1] == W1[1]);

    f32x4 acc0[2][4] = {}, acc1[2][4] = {};
    if (share) {
        for (int hh = 0; hh < nh0; hh++)
            phase4(A0[hh], A1[hh], W0[hh], ch0, t, w, l, At0, At1, Bt, acc0, acc1);
    } else {
        for (int hh = 0; hh < nh0; hh++)
            phase4(A0[hh], nullptr, W0[hh], ch0, t, w, l, At0, At1, Bt, acc0, acc0);
        if (v1)
            for (int hh = 0; hh < nh1; hh++)
                phase4(A1[hh], nullptr, W1[hh], ch0, t, w, l, At0, At1, Bt, acc1, acc1);
    }

    const int h = ch0 + (w & 1) * 16 + (l & 15);
    float bzv[4];
#pragma unroll
    for (int g = 0; g < 4; g++) bzv[g] = bz[g * 512 + h];
    const int ncell = v1 ? 2 : 1;
    for (int s = 0; s < ncell; s++) {
        const int i = ia + s, j = d - i;
        const size_t stI = (size_t)i * 32768, stJ = (size_t)j * 32768;
        f32x4(*acc)[4] = s ? acc1 : acc0;
#pragma unroll
        for (int mt = 0; mt < 2; mt++) {
#pragma unroll
            for (int r = 0; r < 4; r++) {
                int b = (w >> 1) * 32 + mt * 16 + ((l >> 4) << 2) + r;
                float zi = acc[mt][0][r] + bzv[0];
                float zf = acc[mt][1][r] + bzv[1];
                float zg = acc[mt][2][r] + bzv[2];
                float zo = acc[mt][3][r] + bzv[3];
                if (side == 0) {
                    size_t off = stI + (size_t)b * 512 + h;
                    float cold = (j == 0) ? 0.f : sc[off];
                    float c2 = sigm(zf) * cold + sigm(zi) * tanh_(zg);
                    float h2 = sigm(zo) * tanh_(c2);
                    sc[off] = c2;
                    shW[off] = (bf16)h2;
                    if (j == 31) out[off] = h2;  // source_out[i]
                } else {
                    size_t off = stJ + (size_t)b * 512 + h;
                    float cold = (i == 0) ? 0.f : tc[off];
                    float c2 = sigm(zf) * cold + sigm(zi) * tanh_(zg);
                    float h2 = sigm(zo) * tanh_(c2);
                    tc[off] = c2;
                    thW[off] = (bf16)h2;
                    if (i == 31) out[1048576 + off] = h2;  // t_final[0][j]
                }
            }
        }
    }
}

// ---------------- host ----------------

extern "C" void kernel_launch(void* const* d_in, const int* in_sizes, int n_in,
                              void* d_out, int out_size, void* d_ws, size_t ws_size,
                              hipStream_t stream) {
    char* w = (char*)d_ws;
    const size_t MB = 1u << 20;
    const float* src = (const float*)d_in[0];
    const float* tgt = (const float*)d_in[1];
    const float* WH = (const float*)d_in[2];
    const float* bH = (const float*)d_in[3];
    const float* Wk = (const float*)d_in[4];
    const float* Wr = (const float*)d_in[5];
    const float* bl = (const float*)d_in[6];
    float* out = (float*)d_out;

    bf16* srcb = (bf16*)(w + 0 * MB);    // [32][64][512]
    bf16* tgtb = (bf16*)(w + 2 * MB);
    bf16* WHhi = (bf16*)(w + 4 * MB);    // [1024][512]
    bf16* WHlo = (bf16*)(w + 5 * MB);
    bf16* Wrhi = (bf16*)(w + 6 * MB);    // [2048][512] (W_rec^T)
    bf16* Wrlo = (bf16*)(w + 8 * MB);
    bf16* P1 = (bf16*)(w + 10 * MB);     // Wk^T + WHW_hi^T
    bf16* P2 = (bf16*)(w + 12 * MB);     // Wk^T
    bf16* P3 = (bf16*)(w + 14 * MB);     // WHW_lo^T
    bf16* P4 = (bf16*)(w + 16 * MB);     // WHW_hi^T
    bf16* P5 = (bf16*)(w + 18 * MB);     // Wk^T + WHW_lo^T
    float* bz = (float*)(w + 20 * MB);   // [2048]
    bf16* sh = (bf16*)(w + 21 * MB);     // [2][32][64][512] double-buffered
    bf16* th = (bf16*)(w + 25 * MB);
    float* sc = (float*)(w + 29 * MB);   // [32][64][512] fp32
    float* tc = (float*)(w + 33 * MB);   // end: 37 MB

    k_prep<<<1024, BLK, 0, stream>>>(src, tgt, WH, bH, Wk, Wr, bl, srcb, tgtb,
                                     WHhi, WHlo, Wrhi, Wrlo, P2, bz);
    k_gemmP<<<256, BLK, 0, stream>>>(Wrhi, Wrlo, WHhi, WHlo, Wk, P1, P3, P4, P5);

    for (int d = 0; d < 63; d++) {
        int i_lo = d > 31 ? d - 31 : 0;
        int i_hi = d < 31 ? d : 31;
        int Kd = i_hi - i_lo + 1;
        const bf16* shR = sh + (size_t)(d & 1) * 1048576;
        bf16* shW = sh + (size_t)((d + 1) & 1) * 1048576;
        const bf16* thR = th + (size_t)(d & 1) * 1048576;
        bf16* thW = th + (size_t)((d + 1) & 1) * 1048576;
        if (Kd >= 16) {
            int nPair = (Kd + 1) >> 1;
            k_diag4<<<nPair * 32, BLK, 0, stream>>>(d, i_lo, i_hi, srcb, tgtb, P1, P2,
                                                    P3, P4, P5, bz, shR, shW, thR, thW,
                                                    sc, tc, out);
        } else {
            k_diag3<<<Kd * 32, BLK, 0, stream>>>(d, i_lo, srcb, tgtb, P1, P2, P3, P4,
                                                 P5, bz, shR, shW, thR, thW, sc, tc,
                                                 out);
        }
    }
}